// Round 1
// baseline (224.249 us; speedup 1.0000x reference)
//
#include <hip/hip_runtime.h>
#include <hip/hip_bf16.h>

// SeqAttention: banded relative-position attention.
// out[b,i,:] = softmax_k( (q_i . key[i+k] + q_i . pe[:,k]) / 8 ) @ value[i+k,:], k in [0,1024)
//
// Strategy: flash-style tiles. Block = (bh, 64 query rows), 4 waves x 16 rows.
// 17 key-tiles of 64. Positional scores P = Q @ PE^T computed per 64-wide rel
// block (rolling pair in LDS). bf16 MFMA 16x16x32, f32 softmax/accum.

typedef __attribute__((ext_vector_type(8))) short bf16x8;
typedef __attribute__((ext_vector_type(4))) short bf16x4;
typedef __attribute__((ext_vector_type(4))) float f32x4;

#define BHN   64
#define MQ    1024
#define DH    64
#define LS    1024
#define NKEY  2048
#define NTILE 17

__device__ __forceinline__ short f2bf(float f) {
  // RNE f32->bf16 (inputs are finite; no NaN path needed)
  unsigned u = __float_as_uint(f);
  u += 0x7FFFu + ((u >> 16) & 1u);
  return (short)(u >> 16);
}

// key_pe is [1, D, L] row-major; produce peT [L][D] in bf16 for contiguous B-frags.
__global__ void prep_pe_kernel(const float* __restrict__ pe, short* __restrict__ peT) {
  int idx = blockIdx.x * 256 + threadIdx.x;   // 0 .. 65535
  int rel = idx >> 6;
  int d   = idx & 63;
  peT[idx] = f2bf(pe[d * LS + rel]);          // peT[rel*64 + d]
}

__global__ __launch_bounds__(256, 2)
void seq_attn_kernel(const float* __restrict__ Q, const float* __restrict__ K,
                     const float* __restrict__ V, const short* __restrict__ peT,
                     float* __restrict__ Out) {
  // LDS: strides padded for <=2-way bank access (see session notes)
  __shared__ short sK[64 * 72];        // [key][d]  stride 72 bf16
  __shared__ short sPE[64 * 72];       // [rel][d]  stride 72 bf16
  __shared__ short sV[64 * 68];        // [d][key]  stride 68 bf16, 4-chunk XOR swizzle
  __shared__ float sP[2][64 * 67];     // pos scores [row][rel-in-block], stride 67 f32
  __shared__ short sPA[64 * 72];       // softmaxed P for A-operand, [row][key] stride 72

  const int tid  = threadIdx.x;
  const int w    = tid >> 6;           // wave 0..3, owns local rows 16w..16w+15
  const int lane = tid & 63;
  const int li   = lane & 15;
  const int quad = lane >> 4;
  const int bh   = blockIdx.y;
  const int i0   = blockIdx.x * 64;
  const int rbase = w * 16 + quad * 4; // first local row of this lane's C-frags

  // ---- Q A-fragments (A[m=li][k=quad*8+j], two K-steps), f32 -> bf16
  bf16x8 aq[2];
  {
    const float* qp = Q + (size_t)((bh * MQ + i0 + w * 16 + li) * DH) + quad * 8;
#pragma unroll
    for (int ks = 0; ks < 2; ++ks) {
      const float4 f0 = *(const float4*)(qp + ks * 32);
      const float4 f1 = *(const float4*)(qp + ks * 32 + 4);
      bf16x8 a;
      a[0] = f2bf(f0.x); a[1] = f2bf(f0.y); a[2] = f2bf(f0.z); a[3] = f2bf(f0.w);
      a[4] = f2bf(f1.x); a[5] = f2bf(f1.y); a[6] = f2bf(f1.z); a[7] = f2bf(f1.w);
      aq[ks] = a;
    }
  }

  // staging maps
  const int srow = tid >> 2;           // K/PE: 64 rows, 4 threads/row
  const int sdb  = (tid & 3) * 16;     // 16 d per thread
  const int vdb  = (tid & 15) * 4;     // V: 4x4 micro-tile transpose
  const int vkb  = (tid >> 4) * 4;
  const int vch  = (tid >> 4) ^ (tid & 3);  // swizzled 4-key chunk index

  float m_i[4] = {-1e30f, -1e30f, -1e30f, -1e30f};
  float l_i[4] = {0.f, 0.f, 0.f, 0.f};
  f32x4 acco[4];
#pragma unroll
  for (int nt = 0; nt < 4; ++nt) acco[nt] = (f32x4){0.f, 0.f, 0.f, 0.f};

  for (int t = 0; t < NTILE; ++t) {
    const int j0 = i0 + t * 64;
    __syncthreads();   // protect sK/sV/sPE vs previous iteration's readers

    // ---- stage K tile (f32 -> bf16)
    {
      const float* src = K + (size_t)(bh * NKEY + j0 + srow) * DH + sdb;
      const float4 a0 = *(const float4*)(src + 0);
      const float4 a1 = *(const float4*)(src + 4);
      const float4 a2 = *(const float4*)(src + 8);
      const float4 a3 = *(const float4*)(src + 12);
      bf16x8 b0, b1;
      b0[0]=f2bf(a0.x); b0[1]=f2bf(a0.y); b0[2]=f2bf(a0.z); b0[3]=f2bf(a0.w);
      b0[4]=f2bf(a1.x); b0[5]=f2bf(a1.y); b0[6]=f2bf(a1.z); b0[7]=f2bf(a1.w);
      b1[0]=f2bf(a2.x); b1[1]=f2bf(a2.y); b1[2]=f2bf(a2.z); b1[3]=f2bf(a2.w);
      b1[4]=f2bf(a3.x); b1[5]=f2bf(a3.y); b1[6]=f2bf(a3.z); b1[7]=f2bf(a3.w);
      *(bf16x8*)&sK[srow * 72 + sdb]     = b0;
      *(bf16x8*)&sK[srow * 72 + sdb + 8] = b1;
    }
    // ---- stage V tile transposed: sV[d][key], 4x4 in-register micro-transpose
    {
      const float* src = V + (size_t)(bh * NKEY + j0 + vkb) * DH + vdb;
      const float4 r0 = *(const float4*)(src);
      const float4 r1 = *(const float4*)(src + DH);
      const float4 r2 = *(const float4*)(src + 2 * DH);
      const float4 r3 = *(const float4*)(src + 3 * DH);
      bf16x4 c0 = { f2bf(r0.x), f2bf(r1.x), f2bf(r2.x), f2bf(r3.x) };
      bf16x4 c1 = { f2bf(r0.y), f2bf(r1.y), f2bf(r2.y), f2bf(r3.y) };
      bf16x4 c2 = { f2bf(r0.z), f2bf(r1.z), f2bf(r2.z), f2bf(r3.z) };
      bf16x4 c3 = { f2bf(r0.w), f2bf(r1.w), f2bf(r2.w), f2bf(r3.w) };
      *(bf16x4*)&sV[(vdb + 0) * 68 + vch * 4] = c0;
      *(bf16x4*)&sV[(vdb + 1) * 68 + vch * 4] = c1;
      *(bf16x4*)&sV[(vdb + 2) * 68 + vch * 4] = c2;
      *(bf16x4*)&sV[(vdb + 3) * 68 + vch * 4] = c3;
    }
    // ---- stage PE tile (already bf16): rel block t
    if (t < NTILE - 1) {
      const short* src = peT + (size_t)(t * 64 + srow) * DH + sdb;
      const bf16x8 p0 = *(const bf16x8*)(src);
      const bf16x8 p1 = *(const bf16x8*)(src + 8);
      *(bf16x8*)&sPE[srow * 72 + sdb]     = p0;
      *(bf16x8*)&sPE[srow * 72 + sdb + 8] = p1;
    }
    __syncthreads();

    // ---- P_cur = Q @ PE (rel block t); wave-local rows, no barrier needed
    if (t < NTILE - 1) {
      float* Pc = sP[t & 1];
#pragma unroll
      for (int nt = 0; nt < 4; ++nt) {
        f32x4 c = (f32x4){0.f, 0.f, 0.f, 0.f};
#pragma unroll
        for (int ks = 0; ks < 2; ++ks) {
          const bf16x8 b = *(bf16x8*)&sPE[(nt * 16 + li) * 72 + ks * 32 + quad * 8];
          c = __builtin_amdgcn_mfma_f32_16x16x32_bf16(aq[ks], b, c, 0, 0, 0);
        }
#pragma unroll
        for (int r = 0; r < 4; ++r)
          Pc[(rbase + r) * 67 + nt * 16 + li] = c[r];
      }
    }

    // ---- S = Q @ K^T
    f32x4 cs[4];
#pragma unroll
    for (int nt = 0; nt < 4; ++nt) {
      f32x4 c = (f32x4){0.f, 0.f, 0.f, 0.f};
#pragma unroll
      for (int ks = 0; ks < 2; ++ks) {
        const bf16x8 b = *(bf16x8*)&sK[(nt * 16 + li) * 72 + ks * 32 + quad * 8];
        c = __builtin_amdgcn_mfma_f32_16x16x32_bf16(aq[ks], b, c, 0, 0, 0);
      }
      cs[nt] = c;
    }

    // ---- assemble scores: add positional term, scale, band mask
    const float* Pc = sP[t & 1];
    const float* Pp = sP[(t & 1) ^ 1];
    float svv[4][4];
#pragma unroll
    for (int nt = 0; nt < 4; ++nt) {
#pragma unroll
      for (int r = 0; r < 4; ++r) {
        const int row = rbase + r;          // local query row
        const int jc  = nt * 16 + li;       // local key col; rel = 64t + jc - row
        const int dl  = jc - row;           // in [-63, 63]
        const float* psrc = (dl >= 0) ? (Pc + row * 67 + dl)
                                      : (Pp + row * 67 + 64 + dl);
        const float s = (cs[nt][r] + *psrc) * 0.125f;
        const bool invalid = (t == 0 && dl < 0) || (t == NTILE - 1 && dl >= 0);
        svv[nt][r] = invalid ? -1e30f : s;  // select kills any garbage/NaN read
      }
    }

    // ---- online softmax (rows live across the 16 lanes of each quad)
    float p[4][4];
#pragma unroll
    for (int r = 0; r < 4; ++r) {
      float m0 = fmaxf(fmaxf(svv[0][r], svv[1][r]), fmaxf(svv[2][r], svv[3][r]));
      m0 = fmaxf(m0, __shfl_xor(m0, 1));
      m0 = fmaxf(m0, __shfl_xor(m0, 2));
      m0 = fmaxf(m0, __shfl_xor(m0, 4));
      m0 = fmaxf(m0, __shfl_xor(m0, 8));
      const float mn = fmaxf(m_i[r], m0);
      const float al = __expf(m_i[r] - mn);
      m_i[r] = mn;
      float rs = 0.f;
#pragma unroll
      for (int nt = 0; nt < 4; ++nt) {
        p[nt][r] = __expf(svv[nt][r] - mn);
        rs += p[nt][r];
      }
      rs += __shfl_xor(rs, 1);
      rs += __shfl_xor(rs, 2);
      rs += __shfl_xor(rs, 4);
      rs += __shfl_xor(rs, 8);
      l_i[r] = l_i[r] * al + rs;
#pragma unroll
      for (int nt = 0; nt < 4; ++nt) acco[nt][r] *= al;
    }

    // ---- P (C-layout) -> LDS -> A-layout; wave-local, compiler emits lgkmcnt waits
#pragma unroll
    for (int nt = 0; nt < 4; ++nt)
#pragma unroll
      for (int r = 0; r < 4; ++r)
        sPA[(rbase + r) * 72 + nt * 16 + li] = f2bf(p[nt][r]);

    // ---- O += P @ V
#pragma unroll
    for (int ks = 0; ks < 2; ++ks) {
      const bf16x8 ap = *(bf16x8*)&sPA[(w * 16 + li) * 72 + ks * 32 + quad * 8];
#pragma unroll
      for (int nt = 0; nt < 4; ++nt) {
        const int d  = nt * 16 + li;
        const int cb = ks * 8 + quad * 2;
        const int sw = li >> 2;
        const bf16x4 blo = *(bf16x4*)&sV[d * 68 + ((cb)     ^ sw) * 4];
        const bf16x4 bhi = *(bf16x4*)&sV[d * 68 + ((cb + 1) ^ sw) * 4];
        bf16x8 bv;
        bv[0]=blo[0]; bv[1]=blo[1]; bv[2]=blo[2]; bv[3]=blo[3];
        bv[4]=bhi[0]; bv[5]=bhi[1]; bv[6]=bhi[2]; bv[7]=bhi[3];
        acco[nt] = __builtin_amdgcn_mfma_f32_16x16x32_bf16(ap, bv, acco[nt], 0, 0, 0);
      }
    }
  }

  // ---- epilogue: out = O / l
#pragma unroll
  for (int r = 0; r < 4; ++r) {
    const float inv = 1.0f / l_i[r];
#pragma unroll
    for (int nt = 0; nt < 4; ++nt) {
      Out[(size_t)(bh * MQ + i0 + rbase + r) * DH + nt * 16 + li] = acco[nt][r] * inv;
    }
  }
}

extern "C" void kernel_launch(void* const* d_in, const int* in_sizes, int n_in,
                              void* d_out, int out_size, void* d_ws, size_t ws_size,
                              hipStream_t stream) {
  const float* q  = (const float*)d_in[0];  // [64,1024,64]
  const float* k  = (const float*)d_in[1];  // [64,2048,64]
  const float* v  = (const float*)d_in[2];  // [64,2048,64]
  const float* pe = (const float*)d_in[3];  // [1,64,1024]
  float* out = (float*)d_out;               // [64,1024,64] f32
  short* peT = (short*)d_ws;                // [1024][64] bf16 = 128 KiB

  prep_pe_kernel<<<256, 256, 0, stream>>>(pe, peT);
  dim3 grid(MQ / 64, BHN);
  seq_attn_kernel<<<grid, 256, 0, stream>>>(q, k, v, peT, out);
}

// Round 2
// 216.368 us; speedup vs baseline: 1.0364x; 1.0364x over previous
//
#include <hip/hip_runtime.h>
#include <hip/hip_bf16.h>

// SeqAttention: banded relative-position attention.
// out[b,i,:] = softmax_k( (q_i . key[i+k] + q_i . pe[:,k]) / 8 ) @ value[i+k,:], k in [0,1024)
//
// R2: granule-XOR swizzled LDS (conflict-free b128 frags), bf16 sP, 3 blocks/CU,
// bf16 pre-convert of K (pre-swizzled rows) and V (transposed) in d_ws with
// global_load_lds staging, XCD-aware block swizzle. Fallback path (small ws)
// keeps in-kernel f32->bf16 conversion with the same LDS layouts.

typedef __attribute__((ext_vector_type(8))) short bf16x8;
typedef __attribute__((ext_vector_type(4))) short bf16x4;
typedef __attribute__((ext_vector_type(4))) float f32x4;

#define BHN   64
#define MQ    1024
#define DH    64
#define LS    1024
#define NKEY  2048
#define NTILE 17
#define PASTR 68
#define PSTR  68

#define SZ_PE  ((size_t)LS * DH * 2)              // 131072, swizzled bf16 [rel][d]
#define OFF_K  SZ_PE
#define SZ_K   ((size_t)BHN * NKEY * DH * 2)      // bf16, rows pre-swizzled
#define OFF_V  (OFF_K + SZ_K)
#define SZ_V   ((size_t)BHN * DH * NKEY * 2)      // bf16 V^T [bh][d][key]
#define WS_NEED (OFF_V + SZ_V)                    // ~33.7 MB

__device__ __forceinline__ short f2bf(float f) {
  unsigned u = __float_as_uint(f);
  u += 0x7FFFu + ((u >> 16) & 1u);                // RNE (inputs finite)
  return (short)(u >> 16);
}
__device__ __forceinline__ float bf2f(short s) {
  return __uint_as_float(((unsigned)(unsigned short)s) << 16);
}
__device__ __forceinline__ void async_copy16(const void* g, void* l) {
  __builtin_amdgcn_global_load_lds((const __attribute__((address_space(1))) void*)g,
                                   (__attribute__((address_space(3))) void*)l, 16, 0, 0);
}

// pe [1,D,L] -> peT [rel][slot] bf16, 8-short granules swizzled by (rel&7)
__global__ void prep_pe_kernel(const float* __restrict__ pe, short* __restrict__ peT) {
  const int idx = blockIdx.x * 256 + threadIdx.x;   // 65536
  const int rel = idx >> 6, d = idx & 63;
  peT[rel * 64 + (((d >> 3) ^ (rel & 7)) * 8) + (d & 7)] = f2bf(pe[d * LS + rel]);
}

// K f32 [bh*2048][64] -> bf16 rows with granule swizzle by (row&7)
__global__ void prep_k_kernel(const float* __restrict__ K, short* __restrict__ Kb) {
  const size_t i = ((size_t)blockIdx.x * 256 + threadIdx.x) * 4;  // < 8,388,608
  const int row = (int)(i >> 6);
  const int col = (int)(i & 63);
  float4 f = *(const float4*)(K + i);
  bf16x4 b = {f2bf(f.x), f2bf(f.y), f2bf(f.z), f2bf(f.w)};
  *(bf16x4*)(Kb + (size_t)row * 64 + (((col >> 3) ^ (row & 7)) * 8) + (col & 7)) = b;
}

// V f32 [bh][2048][64] -> bf16 V^T [bh][64][2048] via LDS tile transpose
__global__ __launch_bounds__(256) void prep_v_kernel(const float* __restrict__ V,
                                                     short* __restrict__ Vb) {
  __shared__ short st[64 * 68];
  const int bh = blockIdx.y, jt = blockIdx.x;
  const int r = threadIdx.x >> 2, cb = (threadIdx.x & 3) * 16;
  const float* src = V + ((size_t)bh * NKEY + jt * 64 + r) * DH + cb;
#pragma unroll
  for (int c = 0; c < 16; c += 4) {
    float4 f = *(const float4*)(src + c);
    bf16x4 b = {f2bf(f.x), f2bf(f.y), f2bf(f.z), f2bf(f.w)};
    *(bf16x4*)&st[r * 68 + cb + c] = b;
  }
  __syncthreads();
  const int d = threadIdx.x >> 2, kb = (threadIdx.x & 3) * 16;
  __attribute__((aligned(16))) short tmp[16];
#pragma unroll
  for (int j = 0; j < 16; ++j) tmp[j] = st[(kb + j) * 68 + d];
  short* dst = Vb + ((size_t)bh * DH + d) * NKEY + jt * 64 + kb;
  *(bf16x8*)dst = *(bf16x8*)&tmp[0];
  *(bf16x8*)(dst + 8) = *(bf16x8*)&tmp[8];
}

template <bool PRECONV>
__global__ __launch_bounds__(256, 3)
void seq_attn_kernel(const float* __restrict__ Qf, const float* __restrict__ Kf,
                     const float* __restrict__ Vf, const short* __restrict__ peT,
                     const short* __restrict__ Kb, const short* __restrict__ Vb,
                     float* __restrict__ Out) {
  // stride-64 + granule-XOR layouts: slot = (g ^ (row&7)), g = 16B d/key granule.
  __shared__ short sK[64 * 64];        // [key][d-granules swizzled]
  __shared__ short sPE[64 * 64];       // [rel][d-granules swizzled]
  __shared__ short sV[64 * 64];        // [d][key-granules swizzled]
  __shared__ short sPA[64 * PASTR];    // softmaxed P, [row][key]
  __shared__ short sP[2][64 * PSTR];   // pos scores bf16, [row][rel-in-block]

  const int tid  = threadIdx.x;
  const int w    = tid >> 6;
  const int lane = tid & 63;
  const int li   = lane & 15;
  const int quad = lane >> 4;
  // XCD-aware swizzle: 8 consecutive bh per XCD (L2 working set 1MB vs 4MB L2)
  const int linear = blockIdx.y * 16 + blockIdx.x;
  const int slot   = linear >> 3;
  const int bh     = (linear & 7) * 8 + (slot >> 4);
  const int i0     = (slot & 15) * 64;
  const int rbase  = w * 16 + quad * 4;

  // ---- Q A-fragments (A[m=li][k=quad*8+j], two K-steps), f32 -> bf16
  bf16x8 aq[2];
  {
    const float* qp = Qf + (size_t)((bh * MQ + i0 + w * 16 + li) * DH) + quad * 8;
#pragma unroll
    for (int ks = 0; ks < 2; ++ks) {
      const float4 f0 = *(const float4*)(qp + ks * 32);
      const float4 f1 = *(const float4*)(qp + ks * 32 + 4);
      bf16x8 a;
      a[0] = f2bf(f0.x); a[1] = f2bf(f0.y); a[2] = f2bf(f0.z); a[3] = f2bf(f0.w);
      a[4] = f2bf(f1.x); a[5] = f2bf(f1.y); a[6] = f2bf(f1.z); a[7] = f2bf(f1.w);
      aq[ks] = a;
    }
  }

  float m_i[4] = {-1e30f, -1e30f, -1e30f, -1e30f};
  float l_i[4] = {0.f, 0.f, 0.f, 0.f};
  f32x4 acco[4];
#pragma unroll
  for (int nt = 0; nt < 4; ++nt) acco[nt] = (f32x4){0.f, 0.f, 0.f, 0.f};

  for (int t = 0; t < NTILE; ++t) {
    const int j0 = i0 + t * 64;
    __syncthreads();   // protect sK/sV/sPE vs previous iteration's readers

    if constexpr (PRECONV) {
      // K tile: 8KB linear copy (pre-swizzled rows), 2 x 1KB per wave
      {
        const char* gb = (const char*)(Kb + ((size_t)bh * NKEY + j0) * 64);
#pragma unroll
        for (int it = 0; it < 2; ++it) {
          const int c0 = w * 128 + it * 64;
          async_copy16(gb + (size_t)(c0 + lane) * 16, (char*)sK + (size_t)c0 * 16);
        }
      }
      // PE tile: same structure
      if (t < NTILE - 1) {
        const char* gb = (const char*)(peT + (size_t)t * 64 * 64);
#pragma unroll
        for (int it = 0; it < 2; ++it) {
          const int c0 = w * 128 + it * 64;
          async_copy16(gb + (size_t)(c0 + lane) * 16, (char*)sPE + (size_t)c0 * 16);
        }
      }
      // V tile: per-lane gather from V^T rows, swizzle baked into which granule
      // each lane fetches (LDS dest is uniform base + lane*16)
      {
#pragma unroll
        for (int it = 0; it < 2; ++it) {
          const int s = w * 128 + it * 64 + lane;        // slot 0..511
          const int d = s >> 3;
          const int g = (s & 7) ^ (d & 7);               // logical 8-key granule
          const short* gp = Vb + ((size_t)bh * DH + d) * NKEY + j0 + g * 8;
          async_copy16(gp, (char*)sV + (size_t)(w * 128 + it * 64) * 16);
        }
      }
    } else {
      // ---- fallback: stage with in-kernel f32->bf16 conversion
      {
        const int srow = tid >> 2, l0 = tid & 3, sdb = l0 * 16;
        const float* src = Kf + (size_t)(bh * NKEY + j0 + srow) * DH + sdb;
        const float4 a0 = *(const float4*)(src + 0);
        const float4 a1 = *(const float4*)(src + 4);
        const float4 a2 = *(const float4*)(src + 8);
        const float4 a3 = *(const float4*)(src + 12);
        bf16x8 b0, b1;
        b0[0]=f2bf(a0.x); b0[1]=f2bf(a0.y); b0[2]=f2bf(a0.z); b0[3]=f2bf(a0.w);
        b0[4]=f2bf(a1.x); b0[5]=f2bf(a1.y); b0[6]=f2bf(a1.z); b0[7]=f2bf(a1.w);
        b1[0]=f2bf(a2.x); b1[1]=f2bf(a2.y); b1[2]=f2bf(a2.z); b1[3]=f2bf(a2.w);
        b1[4]=f2bf(a3.x); b1[5]=f2bf(a3.y); b1[6]=f2bf(a3.z); b1[7]=f2bf(a3.w);
        const int s7 = srow & 7;
        *(bf16x8*)&sK[srow * 64 + (((2 * l0)     ^ s7) * 8)] = b0;
        *(bf16x8*)&sK[srow * 64 + (((2 * l0 + 1) ^ s7) * 8)] = b1;
      }
      {
        const int vdb = (tid & 15) * 4, vkb = (tid >> 4) * 4;
        const float* src = Vf + (size_t)(bh * NKEY + j0 + vkb) * DH + vdb;
        const float4 r0 = *(const float4*)(src);
        const float4 r1 = *(const float4*)(src + DH);
        const float4 r2 = *(const float4*)(src + 2 * DH);
        const float4 r3 = *(const float4*)(src + 3 * DH);
        bf16x4 cc[4];
        cc[0] = (bf16x4){ f2bf(r0.x), f2bf(r1.x), f2bf(r2.x), f2bf(r3.x) };
        cc[1] = (bf16x4){ f2bf(r0.y), f2bf(r1.y), f2bf(r2.y), f2bf(r3.y) };
        cc[2] = (bf16x4){ f2bf(r0.z), f2bf(r1.z), f2bf(r2.z), f2bf(r3.z) };
        cc[3] = (bf16x4){ f2bf(r0.w), f2bf(r1.w), f2bf(r2.w), f2bf(r3.w) };
        const int g = vkb >> 3, h = (vkb >> 2) & 1;
#pragma unroll
        for (int jj = 0; jj < 4; ++jj) {
          const int d = vdb + jj;
          *(bf16x4*)&sV[d * 64 + ((g ^ (d & 7)) * 8) + h * 4] = cc[jj];
        }
      }
      if (t < NTILE - 1) {
        // peT is already in the swizzled layout: linear copy
        const short* src = peT + (size_t)t * 64 * 64;
        *(bf16x8*)&sPE[tid * 16]     = *(const bf16x8*)(src + tid * 16);
        *(bf16x8*)&sPE[tid * 16 + 8] = *(const bf16x8*)(src + tid * 16 + 8);
      }
    }
    __syncthreads();

    // ---- P_cur = Q @ PE (rel block t); wave-local rows, no barrier needed
    if (t < NTILE - 1) {
      short* Pc = sP[t & 1];
#pragma unroll
      for (int nt = 0; nt < 4; ++nt) {
        f32x4 c = (f32x4){0.f, 0.f, 0.f, 0.f};
#pragma unroll
        for (int ks = 0; ks < 2; ++ks) {
          const int gs = (((ks * 4 + quad) ^ (li & 7)) * 8);
          const bf16x8 b = *(bf16x8*)&sPE[(nt * 16 + li) * 64 + gs];
          c = __builtin_amdgcn_mfma_f32_16x16x32_bf16(aq[ks], b, c, 0, 0, 0);
        }
#pragma unroll
        for (int r = 0; r < 4; ++r)
          Pc[(rbase + r) * PSTR + nt * 16 + li] = f2bf(c[r]);
      }
    }

    // ---- S = Q @ K^T
    f32x4 cs[4];
#pragma unroll
    for (int nt = 0; nt < 4; ++nt) {
      f32x4 c = (f32x4){0.f, 0.f, 0.f, 0.f};
#pragma unroll
      for (int ks = 0; ks < 2; ++ks) {
        const int gs = (((ks * 4 + quad) ^ (li & 7)) * 8);
        const bf16x8 b = *(bf16x8*)&sK[(nt * 16 + li) * 64 + gs];
        c = __builtin_amdgcn_mfma_f32_16x16x32_bf16(aq[ks], b, c, 0, 0, 0);
      }
      cs[nt] = c;
    }

    // ---- assemble scores: positional term (diagonal gather), scale, band mask
    const short* Pc = sP[t & 1];
    const short* Pp = sP[(t & 1) ^ 1];
    float svv[4][4];
#pragma unroll
    for (int nt = 0; nt < 4; ++nt) {
#pragma unroll
      for (int r = 0; r < 4; ++r) {
        const int row = rbase + r;
        const int jc  = nt * 16 + li;
        const int dl  = jc - row;           // in [-63, 63]
        const short pv = (dl >= 0) ? Pc[row * PSTR + dl]
                                   : Pp[row * PSTR + 64 + dl];
        const float s = (cs[nt][r] + bf2f(pv)) * 0.125f;
        const bool invalid = (t == 0 && dl < 0) || (t == NTILE - 1 && dl >= 0);
        svv[nt][r] = invalid ? -1e30f : s;  // select kills garbage reads
      }
    }

    // ---- online softmax (rows live across the 16 lanes of each quad)
    float p[4][4];
#pragma unroll
    for (int r = 0; r < 4; ++r) {
      float m0 = fmaxf(fmaxf(svv[0][r], svv[1][r]), fmaxf(svv[2][r], svv[3][r]));
      m0 = fmaxf(m0, __shfl_xor(m0, 1));
      m0 = fmaxf(m0, __shfl_xor(m0, 2));
      m0 = fmaxf(m0, __shfl_xor(m0, 4));
      m0 = fmaxf(m0, __shfl_xor(m0, 8));
      const float mn = fmaxf(m_i[r], m0);
      const float al = __expf(m_i[r] - mn);
      m_i[r] = mn;
      float rs = 0.f;
#pragma unroll
      for (int nt = 0; nt < 4; ++nt) {
        p[nt][r] = __expf(svv[nt][r] - mn);
        rs += p[nt][r];
      }
      rs += __shfl_xor(rs, 1);
      rs += __shfl_xor(rs, 2);
      rs += __shfl_xor(rs, 4);
      rs += __shfl_xor(rs, 8);
      l_i[r] = l_i[r] * al + rs;
#pragma unroll
      for (int nt = 0; nt < 4; ++nt) acco[nt][r] *= al;
    }

    // ---- P (C-layout) -> LDS -> A-layout; wave-local
#pragma unroll
    for (int nt = 0; nt < 4; ++nt)
#pragma unroll
      for (int r = 0; r < 4; ++r)
        sPA[(rbase + r) * PASTR + nt * 16 + li] = f2bf(p[nt][r]);

    // ---- O += P @ V
#pragma unroll
    for (int ks = 0; ks < 2; ++ks) {
      const int pa = (w * 16 + li) * PASTR + ks * 32 + quad * 8;
      const bf16x4 a0 = *(bf16x4*)&sPA[pa];
      const bf16x4 a1 = *(bf16x4*)&sPA[pa + 4];
      bf16x8 ap;
      ap[0]=a0[0]; ap[1]=a0[1]; ap[2]=a0[2]; ap[3]=a0[3];
      ap[4]=a1[0]; ap[5]=a1[1]; ap[6]=a1[2]; ap[7]=a1[3];
#pragma unroll
      for (int nt = 0; nt < 4; ++nt) {
        const int d  = nt * 16 + li;
        const int gs = (((ks * 4 + quad) ^ (d & 7)) * 8);
        const bf16x8 bv = *(bf16x8*)&sV[d * 64 + gs];
        acco[nt] = __builtin_amdgcn_mfma_f32_16x16x32_bf16(ap, bv, acco[nt], 0, 0, 0);
      }
    }
  }

  // ---- epilogue: out = O / l
#pragma unroll
  for (int r = 0; r < 4; ++r) {
    const float inv = 1.0f / l_i[r];
#pragma unroll
    for (int nt = 0; nt < 4; ++nt) {
      Out[(size_t)(bh * MQ + i0 + rbase + r) * DH + nt * 16 + li] = acco[nt][r] * inv;
    }
  }
}

extern "C" void kernel_launch(void* const* d_in, const int* in_sizes, int n_in,
                              void* d_out, int out_size, void* d_ws, size_t ws_size,
                              hipStream_t stream) {
  const float* q  = (const float*)d_in[0];  // [64,1024,64]
  const float* k  = (const float*)d_in[1];  // [64,2048,64]
  const float* v  = (const float*)d_in[2];  // [64,2048,64]
  const float* pe = (const float*)d_in[3];  // [1,64,1024]
  float* out = (float*)d_out;               // [64,1024,64] f32
  short* peT = (short*)d_ws;
  short* Kb  = (short*)((char*)d_ws + OFF_K);
  short* Vb  = (short*)((char*)d_ws + OFF_V);
  const bool preconv = ws_size >= WS_NEED;  // constant across calls: capture-safe

  prep_pe_kernel<<<256, 256, 0, stream>>>(pe, peT);
  dim3 grid(MQ / 64, BHN);
  if (preconv) {
    prep_k_kernel<<<8192, 256, 0, stream>>>(k, Kb);
    prep_v_kernel<<<dim3(32, 64), 256, 0, stream>>>(v, Vb);
    seq_attn_kernel<true><<<grid, 256, 0, stream>>>(q, k, v, peT, Kb, Vb, out);
  } else {
    seq_attn_kernel<false><<<grid, 256, 0, stream>>>(q, k, v, peT, Kb, Vb, out);
  }
}

// Round 4
// 182.510 us; speedup vs baseline: 1.2287x; 1.1855x over previous
//
#include <hip/hip_runtime.h>
#include <hip/hip_bf16.h>

// SeqAttention: banded relative-position attention.
// out[b,i,:] = softmax_k( (q_i . key[i+k] + q_i . pe[:,k]) / 8 ) @ value[i+k,:], k in [0,1024)
//
// R4: fixes R3's wave-offset bug in the positional diagonal gather.
// Each wave computes its P = Q@PE^T over a per-wave SHIFTED rel window
// [64t-16w, 64t-16w+63] (sPE = 2-slot circular buffer of PE blocks), so the
// gather needs only compile-time register indices: pos(nt) = ge ? curPw[nt]
// : (nt ? curPw[nt-1] : prevw3), 20 shuffles/tile. No-max softmax (bounded
// scores). LDS = 40KB exactly -> 4 blocks/CU, grid 1024 = 4/CU (no tail).

typedef __attribute__((ext_vector_type(8))) short bf16x8;
typedef __attribute__((ext_vector_type(4))) short bf16x4;
typedef __attribute__((ext_vector_type(4))) float f32x4;

#define BHN   64
#define MQ    1024
#define DH    64
#define LS    1024
#define NKEY  2048
#define NTILE 17

#define SZ_PE  ((size_t)LS * DH * 2)              // 131072, swizzled bf16 [rel][d]
#define OFF_K  SZ_PE
#define SZ_K   ((size_t)BHN * NKEY * DH * 2)      // bf16, rows pre-swizzled
#define OFF_V  (OFF_K + SZ_K)
#define SZ_V   ((size_t)BHN * DH * NKEY * 2)      // bf16 V^T [bh][d][key]
#define WS_NEED (OFF_V + SZ_V)                    // ~33.7 MB

// 0.125 (1/sqrt(64)) * log2(e): fold scale into exp2 argument
#define SCL_LOG2E 0.18033688011112042f

__device__ __forceinline__ short f2bf(float f) {
  unsigned u = __float_as_uint(f);
  u += 0x7FFFu + ((u >> 16) & 1u);                // RNE (inputs finite)
  return (short)(u >> 16);
}
__device__ __forceinline__ void async_copy16(const void* g, void* l) {
  __builtin_amdgcn_global_load_lds((const __attribute__((address_space(1))) void*)g,
                                   (__attribute__((address_space(3))) void*)l, 16, 0, 0);
}

// pe [1,D,L] -> peT [rel][slot] bf16, 8-short granules swizzled by (rel&7)
__global__ void prep_pe_kernel(const float* __restrict__ pe, short* __restrict__ peT) {
  const int idx = blockIdx.x * 256 + threadIdx.x;   // 65536
  const int rel = idx >> 6, d = idx & 63;
  peT[rel * 64 + (((d >> 3) ^ (rel & 7)) * 8) + (d & 7)] = f2bf(pe[d * LS + rel]);
}

// K f32 [bh*2048][64] -> bf16 rows with granule swizzle by (row&7)
__global__ void prep_k_kernel(const float* __restrict__ K, short* __restrict__ Kb) {
  const size_t i = ((size_t)blockIdx.x * 256 + threadIdx.x) * 4;  // < 8,388,608
  const int row = (int)(i >> 6);
  const int col = (int)(i & 63);
  float4 f = *(const float4*)(K + i);
  bf16x4 b = {f2bf(f.x), f2bf(f.y), f2bf(f.z), f2bf(f.w)};
  *(bf16x4*)(Kb + (size_t)row * 64 + (((col >> 3) ^ (row & 7)) * 8) + (col & 7)) = b;
}

// V f32 [bh][2048][64] -> bf16 V^T [bh][64][2048] via LDS tile transpose
__global__ __launch_bounds__(256) void prep_v_kernel(const float* __restrict__ V,
                                                     short* __restrict__ Vb) {
  __shared__ short st[64 * 68];
  const int bh = blockIdx.y, jt = blockIdx.x;
  const int r = threadIdx.x >> 2, cb = (threadIdx.x & 3) * 16;
  const float* src = V + ((size_t)bh * NKEY + jt * 64 + r) * DH + cb;
#pragma unroll
  for (int c = 0; c < 16; c += 4) {
    float4 f = *(const float4*)(src + c);
    bf16x4 b = {f2bf(f.x), f2bf(f.y), f2bf(f.z), f2bf(f.w)};
    *(bf16x4*)&st[r * 68 + cb + c] = b;
  }
  __syncthreads();
  const int d = threadIdx.x >> 2, kb = (threadIdx.x & 3) * 16;
  __attribute__((aligned(16))) short tmp[16];
#pragma unroll
  for (int j = 0; j < 16; ++j) tmp[j] = st[(kb + j) * 68 + d];
  short* dst = Vb + ((size_t)bh * DH + d) * NKEY + jt * 64 + kb;
  *(bf16x8*)dst = *(bf16x8*)&tmp[0];
  *(bf16x8*)(dst + 8) = *(bf16x8*)&tmp[8];
}

template <bool PRECONV>
__global__ __launch_bounds__(256, 4)
void seq_attn_kernel(const float* __restrict__ Qf, const float* __restrict__ Kf,
                     const float* __restrict__ Vf, const short* __restrict__ peT,
                     const short* __restrict__ Kb, const short* __restrict__ Vb,
                     float* __restrict__ Out) {
  // stride-64 + granule-XOR layouts: slot = (g ^ (row&7)), g = 16B d/key granule.
  __shared__ short sK[64 * 64];        // [key][d-granules swizzled]         8KB
  __shared__ short sPE[2 * 64 * 64];   // 2-slot circular PE blocks          16KB
  __shared__ short sV[64 * 64];        // [d][key-granules swizzled]         8KB
  __shared__ short sPA[64 * 64];       // softmaxed P, granule-XOR (row>>1)  8KB
  // total 40KB = 160KB / 4 blocks exactly

  const int tid  = threadIdx.x;
  const int w    = tid >> 6;
  const int lane = tid & 63;
  const int li   = lane & 15;
  const int quad = lane >> 4;
  // XCD-aware swizzle: 8 consecutive bh per XCD (Kb+Vb working set = 4MB = L2)
  const int linear = blockIdx.y * 16 + blockIdx.x;
  const int slot   = linear >> 3;
  const int bh     = (linear & 7) * 8 + (slot >> 4);
  const int i0     = (slot & 15) * 64;
  const int rbase  = w * 16 + quad * 4;

  // ---- Q A-fragments (A[m=li][k=quad*8+j], two K-steps), f32 -> bf16
  bf16x8 aq[2];
  {
    const float* qp = Qf + (size_t)((bh * MQ + i0 + w * 16 + li) * DH) + quad * 8;
#pragma unroll
    for (int ks = 0; ks < 2; ++ks) {
      const float4 f0 = *(const float4*)(qp + ks * 32);
      const float4 f1 = *(const float4*)(qp + ks * 32 + 4);
      bf16x8 a;
      a[0] = f2bf(f0.x); a[1] = f2bf(f0.y); a[2] = f2bf(f0.z); a[3] = f2bf(f0.w);
      a[4] = f2bf(f1.x); a[5] = f2bf(f1.y); a[6] = f2bf(f1.z); a[7] = f2bf(f1.w);
      aq[ks] = a;
    }
  }

  float l_i[4] = {0.f, 0.f, 0.f, 0.f};
  f32x4 acco[4];
#pragma unroll
  for (int nt = 0; nt < 4; ++nt) acco[nt] = (f32x4){0.f, 0.f, 0.f, 0.f};

  f32x4 curPw[4];   // P over rel cols (4t-w+m)*16.., m=0..3 (per-wave window)
  f32x4 prevw3;     // previous tile's curPw[3] = rel col 4t-w-1
  prevw3 = (f32x4){0.f, 0.f, 0.f, 0.f};

  for (int t = 0; t < NTILE; ++t) {
    const int j0 = i0 + t * 64;
    __syncthreads();   // protect sK/sV/sPE vs previous iteration's readers

    if constexpr (PRECONV) {
      {  // K tile: 8KB linear copy (pre-swizzled rows)
        const char* gb = (const char*)(Kb + ((size_t)bh * NKEY + j0) * 64);
#pragma unroll
        for (int it = 0; it < 2; ++it) {
          const int c0 = w * 128 + it * 64;
          async_copy16(gb + (size_t)(c0 + lane) * 16, (char*)sK + (size_t)c0 * 16);
        }
      }
      if (t < NTILE - 1) {  // PE block t -> circular slot t&1
        const char* gb = (const char*)(peT + (size_t)t * 64 * 64);
        char* db = (char*)sPE + (size_t)(t & 1) * 8192;
#pragma unroll
        for (int it = 0; it < 2; ++it) {
          const int c0 = w * 128 + it * 64;
          async_copy16(gb + (size_t)(c0 + lane) * 16, db + (size_t)c0 * 16);
        }
      }
      {  // V tile: per-lane gather from V^T rows, swizzle baked into source granule
#pragma unroll
        for (int it = 0; it < 2; ++it) {
          const int s = w * 128 + it * 64 + lane;        // slot 0..511
          const int d = s >> 3;
          const int g = (s & 7) ^ (d & 7);               // logical 8-key granule
          const short* gp = Vb + ((size_t)bh * DH + d) * NKEY + j0 + g * 8;
          async_copy16(gp, (char*)sV + (size_t)(w * 128 + it * 64) * 16);
        }
      }
    } else {
      // ---- fallback: stage with in-kernel f32->bf16 conversion
      {
        const int srow = tid >> 2, l0 = tid & 3, sdb = l0 * 16;
        const float* src = Kf + (size_t)(bh * NKEY + j0 + srow) * DH + sdb;
        const float4 a0 = *(const float4*)(src + 0);
        const float4 a1 = *(const float4*)(src + 4);
        const float4 a2 = *(const float4*)(src + 8);
        const float4 a3 = *(const float4*)(src + 12);
        bf16x8 b0, b1;
        b0[0]=f2bf(a0.x); b0[1]=f2bf(a0.y); b0[2]=f2bf(a0.z); b0[3]=f2bf(a0.w);
        b0[4]=f2bf(a1.x); b0[5]=f2bf(a1.y); b0[6]=f2bf(a1.z); b0[7]=f2bf(a1.w);
        b1[0]=f2bf(a2.x); b1[1]=f2bf(a2.y); b1[2]=f2bf(a2.z); b1[3]=f2bf(a2.w);
        b1[4]=f2bf(a3.x); b1[5]=f2bf(a3.y); b1[6]=f2bf(a3.z); b1[7]=f2bf(a3.w);
        const int s7 = srow & 7;
        *(bf16x8*)&sK[srow * 64 + (((2 * l0)     ^ s7) * 8)] = b0;
        *(bf16x8*)&sK[srow * 64 + (((2 * l0 + 1) ^ s7) * 8)] = b1;
      }
      {
        const int vdb = (tid & 15) * 4, vkb = (tid >> 4) * 4;
        const float* src = Vf + (size_t)(bh * NKEY + j0 + vkb) * DH + vdb;
        const float4 r0 = *(const float4*)(src);
        const float4 r1 = *(const float4*)(src + DH);
        const float4 r2 = *(const float4*)(src + 2 * DH);
        const float4 r3 = *(const float4*)(src + 3 * DH);
        bf16x4 cc[4];
        cc[0] = (bf16x4){ f2bf(r0.x), f2bf(r1.x), f2bf(r2.x), f2bf(r3.x) };
        cc[1] = (bf16x4){ f2bf(r0.y), f2bf(r1.y), f2bf(r2.y), f2bf(r3.y) };
        cc[2] = (bf16x4){ f2bf(r0.z), f2bf(r1.z), f2bf(r2.z), f2bf(r3.z) };
        cc[3] = (bf16x4){ f2bf(r0.w), f2bf(r1.w), f2bf(r2.w), f2bf(r3.w) };
        const int g = vkb >> 3, h = (vkb >> 2) & 1;
#pragma unroll
        for (int jj = 0; jj < 4; ++jj) {
          const int d = vdb + jj;
          *(bf16x4*)&sV[d * 64 + ((g ^ (d & 7)) * 8) + h * 4] = cc[jj];
        }
      }
      if (t < NTILE - 1) {
        const short* src = peT + (size_t)t * 64 * 64;   // already swizzled
        short* db = sPE + (size_t)(t & 1) * 4096;
        *(bf16x8*)&db[tid * 16]     = *(const bf16x8*)(src + tid * 16);
        *(bf16x8*)&db[tid * 16 + 8] = *(const bf16x8*)(src + tid * 16 + 8);
      }
    }
    __syncthreads();

    // ---- curPw[m] = Q @ PE over rel col (4t-w+m)*16..+15 (per-wave window).
    // Out-of-range cols (t=0 m<w, t=16 high cols) read defined-but-stale LDS
    // and are killed by the band mask below (bitwise select, NaN-safe).
#pragma unroll
    for (int m = 0; m < 4; ++m) {
      const int colIdx = 4 * t - w + m;
      const int base = ((colIdx >> 2) & 1) * 4096 + ((colIdx & 3) * 16 + li) * 64;
      f32x4 c = (f32x4){0.f, 0.f, 0.f, 0.f};
#pragma unroll
      for (int ks = 0; ks < 2; ++ks) {
        const int gs = (((ks * 4 + quad) ^ (li & 7)) * 8);
        const bf16x8 b = *(bf16x8*)&sPE[base + gs];
        c = __builtin_amdgcn_mfma_f32_16x16x32_bf16(aq[ks], b, c, 0, 0, 0);
      }
      curPw[m] = c;
    }

    // ---- S = Q @ K^T
    f32x4 cs[4];
#pragma unroll
    for (int nt = 0; nt < 4; ++nt) {
      f32x4 c = (f32x4){0.f, 0.f, 0.f, 0.f};
#pragma unroll
      for (int ks = 0; ks < 2; ++ks) {
        const int gs = (((ks * 4 + quad) ^ (li & 7)) * 8);
        const bf16x8 b = *(bf16x8*)&sK[(nt * 16 + li) * 64 + gs];
        c = __builtin_amdgcn_mfma_f32_16x16x32_bf16(aq[ks], b, c, 0, 0, 0);
      }
      cs[nt] = c;
    }

    // ---- diagonal gather + no-max softmax.
    // dl = jc - row = (nt-w)*16 + e, e = li - quad*4 - r.  Needed P value:
    // rel col (4t+nt-w) (e>=0) or (4t+nt-w-1) (e<0) == curPw[nt] / curPw[nt-1]
    // / prevw3 -- compile-time indices thanks to the shifted window.
#pragma unroll
    for (int r = 0; r < 4; ++r) {
      const int e       = li - quad * 4 - r;          // in [-15, 15]
      const bool ge     = (e >= 0);
      const int srcLane = quad * 16 + (e & 15);
      const float shm = __shfl(prevw3[r],    srcLane);
      const float sh0 = __shfl(curPw[0][r], srcLane);
      const float sh1 = __shfl(curPw[1][r], srcLane);
      const float sh2 = __shfl(curPw[2][r], srcLane);
      const float sh3 = __shfl(curPw[3][r], srcLane);
      const float pos0 = ge ? sh0 : shm;
      const float pos1 = ge ? sh1 : sh0;
      const float pos2 = ge ? sh2 : sh1;
      const float pos3 = ge ? sh3 : sh2;
      float p0 = __builtin_exp2f((cs[0][r] + pos0) * SCL_LOG2E);
      float p1 = __builtin_exp2f((cs[1][r] + pos1) * SCL_LOG2E);
      float p2 = __builtin_exp2f((cs[2][r] + pos2) * SCL_LOG2E);
      float p3 = __builtin_exp2f((cs[3][r] + pos3) * SCL_LOG2E);
      if (t == 0) {                 // valid iff dl>=0: nt>w || (nt==w && ge)
        p0 = (0 > w || (0 == w && ge)) ? p0 : 0.f;
        p1 = (1 > w || (1 == w && ge)) ? p1 : 0.f;
        p2 = (2 > w || (2 == w && ge)) ? p2 : 0.f;
        p3 = (3 > w || (3 == w && ge)) ? p3 : 0.f;
      } else if (t == NTILE - 1) {  // valid iff dl<0: nt<w || (nt==w && !ge)
        p0 = (0 < w || (0 == w && !ge)) ? p0 : 0.f;
        p1 = (1 < w || (1 == w && !ge)) ? p1 : 0.f;
        p2 = (2 < w || (2 == w && !ge)) ? p2 : 0.f;
        p3 = (3 < w || (3 == w && !ge)) ? p3 : 0.f;
      }
      l_i[r] += (p0 + p1) + (p2 + p3);
      // store to sPA (A-layout), granule-XOR by (row>>1)&7; wave-local rows
      const int rowA = rbase + r;
      const int sw = (rowA >> 1) & 7;
      sPA[rowA * 64 + (((0 + (li >> 3)) ^ sw) * 8) + (li & 7)] = f2bf(p0);
      sPA[rowA * 64 + (((2 + (li >> 3)) ^ sw) * 8) + (li & 7)] = f2bf(p1);
      sPA[rowA * 64 + (((4 + (li >> 3)) ^ sw) * 8) + (li & 7)] = f2bf(p2);
      sPA[rowA * 64 + (((6 + (li >> 3)) ^ sw) * 8) + (li & 7)] = f2bf(p3);
    }
    prevw3 = curPw[3];

    // ---- O += P @ V  (A-frag from sPA, single b128 per ks)
#pragma unroll
    for (int ks = 0; ks < 2; ++ks) {
      const int rowA = w * 16 + li;
      const bf16x8 ap =
          *(bf16x8*)&sPA[rowA * 64 + (((ks * 4 + quad) ^ ((rowA >> 1) & 7)) * 8)];
#pragma unroll
      for (int nt = 0; nt < 4; ++nt) {
        const int d  = nt * 16 + li;
        const int gs = (((ks * 4 + quad) ^ (d & 7)) * 8);
        const bf16x8 bv = *(bf16x8*)&sV[d * 64 + gs];
        acco[nt] = __builtin_amdgcn_mfma_f32_16x16x32_bf16(ap, bv, acco[nt], 0, 0, 0);
      }
    }
  }

  // ---- epilogue: reduce l across the 16 lanes holding each row, out = O / l
#pragma unroll
  for (int r = 0; r < 4; ++r) {
    float l = l_i[r];
    l += __shfl_xor(l, 1);
    l += __shfl_xor(l, 2);
    l += __shfl_xor(l, 4);
    l += __shfl_xor(l, 8);
    const float inv = 1.0f / l;
#pragma unroll
    for (int nt = 0; nt < 4; ++nt) {
      Out[(size_t)(bh * MQ + i0 + rbase + r) * DH + nt * 16 + li] = acco[nt][r] * inv;
    }
  }
}

extern "C" void kernel_launch(void* const* d_in, const int* in_sizes, int n_in,
                              void* d_out, int out_size, void* d_ws, size_t ws_size,
                              hipStream_t stream) {
  const float* q  = (const float*)d_in[0];  // [64,1024,64]
  const float* k  = (const float*)d_in[1];  // [64,2048,64]
  const float* v  = (const float*)d_in[2];  // [64,2048,64]
  const float* pe = (const float*)d_in[3];  // [1,64,1024]
  float* out = (float*)d_out;               // [64,1024,64] f32
  short* peT = (short*)d_ws;
  short* Kb  = (short*)((char*)d_ws + OFF_K);
  short* Vb  = (short*)((char*)d_ws + OFF_V);
  const bool preconv = ws_size >= WS_NEED;  // constant across calls: capture-safe

  prep_pe_kernel<<<256, 256, 0, stream>>>(pe, peT);
  dim3 grid(MQ / 64, BHN);
  if (preconv) {
    prep_k_kernel<<<8192, 256, 0, stream>>>(k, Kb);
    prep_v_kernel<<<dim3(32, 64), 256, 0, stream>>>(v, Vb);
    seq_attn_kernel<true><<<grid, 256, 0, stream>>>(q, k, v, peT, Kb, Vb, out);
  } else {
    seq_attn_kernel<false><<<grid, 256, 0, stream>>>(q, k, v, peT, Kb, Vb, out);
  }
}

// Round 5
// 178.038 us; speedup vs baseline: 1.2596x; 1.0251x over previous
//
#include <hip/hip_runtime.h>
#include <hip/hip_bf16.h>

// SeqAttention: banded relative-position attention.
// out[b,i,:] = softmax_k( (q_i . key[i+k] + q_i . pe[:,k]) / 8 ) @ value[i+k,:], k in [0,1024)
//
// R5: kernel is LDS-pipe bound (R4: DS cyc model = 76% of runtime, conflicts 0).
// Cuts: (1) kappa-permuted key order for the P@V contraction -> P written as
// ds_write_b64 (4/r -> was 16 b16); V pre-permuted in prep to match.
// (2) positional gather shuffles packed bf16x2: 5 -> 3 per r.
// (3) prep fused into one kernel. Layout/mask logic otherwise identical to R4.

typedef __attribute__((ext_vector_type(8))) short bf16x8;
typedef __attribute__((ext_vector_type(4))) short bf16x4;
typedef __attribute__((ext_vector_type(4))) float f32x4;

#define BHN   64
#define MQ    1024
#define DH    64
#define LS    1024
#define NKEY  2048
#define NTILE 17

#define SZ_PE  ((size_t)LS * DH * 2)              // 131072, swizzled bf16 [rel][d]
#define OFF_K  SZ_PE
#define SZ_K   ((size_t)BHN * NKEY * DH * 2)      // bf16, rows pre-swizzled
#define OFF_V  (OFF_K + SZ_K)
#define SZ_V   ((size_t)BHN * DH * NKEY * 2)      // bf16 V^T [bh][d][kappa-key]
#define WS_NEED (OFF_V + SZ_V)                    // ~33.7 MB

// 0.125 (1/sqrt(64)) * log2(e): fold scale into exp2 argument
#define SCL_LOG2E 0.18033688011112042f

__device__ __forceinline__ short f2bf(float f) {
  unsigned u = __float_as_uint(f);
  u += 0x7FFFu + ((u >> 16) & 1u);                // RNE (inputs finite)
  return (short)(u >> 16);
}
__device__ __forceinline__ float bf2f(short s) {
  return __uint_as_float(((unsigned)(unsigned short)s) << 16);
}
__device__ __forceinline__ unsigned packbf(float a, float b) {
  return (unsigned)(unsigned short)f2bf(a) | ((unsigned)(unsigned short)f2bf(b) << 16);
}
__device__ __forceinline__ void async_copy16(const void* g, void* l) {
  __builtin_amdgcn_global_load_lds((const __attribute__((address_space(1))) void*)g,
                                   (__attribute__((address_space(3))) void*)l, 16, 0, 0);
}

// ---- fused prep: [0,256) PE, [256,2304) K, [2304,4352) V
// PE: [1,D,L] f32 -> peT [rel][d] bf16, granule-swizzled by (rel&7)
// K : [bh*2048][64] f32 -> bf16 rows, granule-swizzled by (row&7)
// V : [bh][2048][64] f32 -> bf16 V^T [bh][64][2048], key dim kappa-permuted
//     per 64-block: kappa = (k&15)*4 + (k>>4)  (inverse k = (kap&3)*16 + (kap>>2))
__global__ __launch_bounds__(256)
void prep_fused(const float* __restrict__ pe, const float* __restrict__ K,
                const float* __restrict__ V, short* __restrict__ peT,
                short* __restrict__ Kb, short* __restrict__ Vb) {
  __shared__ short st[64 * 68];
  const int bx = blockIdx.x;
  if (bx < 256) {
    const int idx = bx * 256 + threadIdx.x;       // 65536
    const int rel = idx >> 6, d = idx & 63;
    peT[rel * 64 + (((d >> 3) ^ (rel & 7)) * 8) + (d & 7)] = f2bf(pe[d * LS + rel]);
  } else if (bx < 2304) {
    const size_t i = ((size_t)(bx - 256) * 256 + threadIdx.x) * 16;  // < 8,388,608
    const int row = (int)(i >> 6);
    const int c16 = (int)(i & 63);                // 0,16,32,48
    const float4 f0 = *(const float4*)(K + i);
    const float4 f1 = *(const float4*)(K + i + 4);
    const float4 f2 = *(const float4*)(K + i + 8);
    const float4 f3 = *(const float4*)(K + i + 12);
    bf16x8 b0, b1;
    b0[0]=f2bf(f0.x); b0[1]=f2bf(f0.y); b0[2]=f2bf(f0.z); b0[3]=f2bf(f0.w);
    b0[4]=f2bf(f1.x); b0[5]=f2bf(f1.y); b0[6]=f2bf(f1.z); b0[7]=f2bf(f1.w);
    b1[0]=f2bf(f2.x); b1[1]=f2bf(f2.y); b1[2]=f2bf(f2.z); b1[3]=f2bf(f2.w);
    b1[4]=f2bf(f3.x); b1[5]=f2bf(f3.y); b1[6]=f2bf(f3.z); b1[7]=f2bf(f3.w);
    const int s7 = row & 7;
    short* dst = Kb + (size_t)row * 64;
    *(bf16x8*)&dst[(((c16 >> 3))     ^ s7) * 8] = b0;
    *(bf16x8*)&dst[(((c16 >> 3) + 1) ^ s7) * 8] = b1;
  } else {
    const int b  = bx - 2304;                     // 0..2047
    const int bh = b >> 5, jt = b & 31;
    {  // phase 1: stage 64x64 tile [key][d], f32->bf16
      const int r = threadIdx.x >> 2, cb = (threadIdx.x & 3) * 16;
      const float* src = V + ((size_t)bh * NKEY + jt * 64 + r) * DH + cb;
#pragma unroll
      for (int c = 0; c < 16; c += 4) {
        float4 f = *(const float4*)(src + c);
        bf16x4 v = {f2bf(f.x), f2bf(f.y), f2bf(f.z), f2bf(f.w)};
        *(bf16x4*)&st[r * 68 + cb + c] = v;
      }
    }
    __syncthreads();
    {  // phase 2: transpose + kappa-permute, contiguous b128 writes
      const int d = threadIdx.x >> 2, kapb = (threadIdx.x & 3) * 16;
      __attribute__((aligned(16))) short tmp[16];
#pragma unroll
      for (int j = 0; j < 16; ++j) {
        const int kap = kapb + j;
        const int k   = (kap & 3) * 16 + (kap >> 2);
        tmp[j] = st[k * 68 + d];
      }
      short* dst = Vb + ((size_t)bh * DH + d) * NKEY + jt * 64 + kapb;
      *(bf16x8*)dst       = *(bf16x8*)&tmp[0];
      *(bf16x8*)(dst + 8) = *(bf16x8*)&tmp[8];
    }
  }
}

template <bool PRECONV>
__global__ __launch_bounds__(256, 4)
void seq_attn_kernel(const float* __restrict__ Qf, const float* __restrict__ Kf,
                     const float* __restrict__ Vf, const short* __restrict__ peT,
                     const short* __restrict__ Kb, const short* __restrict__ Vb,
                     float* __restrict__ Out) {
  // stride-64 + granule-XOR layouts: slot = (g ^ (row&7)), g = 16B granule.
  __shared__ short sK[64 * 64];        // [key][d-granules swizzled]         8KB
  __shared__ short sPE[2 * 64 * 64];   // 2-slot circular PE blocks          16KB
  __shared__ short sV[64 * 64];        // [d][kappa-granules swizzled]       8KB
  __shared__ short sPA[64 * 64];       // P, [row][kappa], b64-writable      8KB
  // total 40KB = 160KB / 4 blocks exactly

  const int tid  = threadIdx.x;
  const int w    = tid >> 6;
  const int lane = tid & 63;
  const int li   = lane & 15;
  const int quad = lane >> 4;
  // XCD-aware swizzle: 8 consecutive bh per XCD (Kb+Vb working set = 4MB = L2)
  const int linear = blockIdx.y * 16 + blockIdx.x;
  const int slot   = linear >> 3;
  const int bh     = (linear & 7) * 8 + (slot >> 4);
  const int i0     = (slot & 15) * 64;
  const int rbase  = w * 16 + quad * 4;

  // ---- Q A-fragments (A[m=li][k=quad*8+j], two K-steps), f32 -> bf16
  bf16x8 aq[2];
  {
    const float* qp = Qf + (size_t)((bh * MQ + i0 + w * 16 + li) * DH) + quad * 8;
#pragma unroll
    for (int ks = 0; ks < 2; ++ks) {
      const float4 f0 = *(const float4*)(qp + ks * 32);
      const float4 f1 = *(const float4*)(qp + ks * 32 + 4);
      bf16x8 a;
      a[0] = f2bf(f0.x); a[1] = f2bf(f0.y); a[2] = f2bf(f0.z); a[3] = f2bf(f0.w);
      a[4] = f2bf(f1.x); a[5] = f2bf(f1.y); a[6] = f2bf(f1.z); a[7] = f2bf(f1.w);
      aq[ks] = a;
    }
  }

  float l_i[4] = {0.f, 0.f, 0.f, 0.f};
  f32x4 acco[4];
#pragma unroll
  for (int nt = 0; nt < 4; ++nt) acco[nt] = (f32x4){0.f, 0.f, 0.f, 0.f};

  f32x4 curPw[4];   // P over rel cols (4t-w+m)*16.., m=0..3 (per-wave window)
  f32x4 prevw3;     // previous tile's curPw[3] = rel col 4t-w-1
  prevw3 = (f32x4){0.f, 0.f, 0.f, 0.f};

  for (int t = 0; t < NTILE; ++t) {
    const int j0 = i0 + t * 64;
    __syncthreads();   // protect sK/sV/sPE vs previous iteration's readers

    if constexpr (PRECONV) {
      {  // K tile: 8KB linear copy (pre-swizzled rows)
        const char* gb = (const char*)(Kb + ((size_t)bh * NKEY + j0) * 64);
#pragma unroll
        for (int it = 0; it < 2; ++it) {
          const int c0 = w * 128 + it * 64;
          async_copy16(gb + (size_t)(c0 + lane) * 16, (char*)sK + (size_t)c0 * 16);
        }
      }
      if (t < NTILE - 1) {  // PE block t -> circular slot t&1
        const char* gb = (const char*)(peT + (size_t)t * 64 * 64);
        char* db = (char*)sPE + (size_t)(t & 1) * 8192;
#pragma unroll
        for (int it = 0; it < 2; ++it) {
          const int c0 = w * 128 + it * 64;
          async_copy16(gb + (size_t)(c0 + lane) * 16, db + (size_t)c0 * 16);
        }
      }
      {  // V tile: gather from kappa-permuted V^T rows; swizzle via source granule
#pragma unroll
        for (int it = 0; it < 2; ++it) {
          const int s = w * 128 + it * 64 + lane;        // slot 0..511
          const int d = s >> 3;
          const int g = (s & 7) ^ (d & 7);               // logical kappa-granule
          const short* gp = Vb + ((size_t)bh * DH + d) * NKEY + j0 + g * 8;
          async_copy16(gp, (char*)sV + (size_t)(w * 128 + it * 64) * 16);
        }
      }
    } else {
      // ---- fallback: stage with in-kernel f32->bf16 conversion (correct, unused
      // when ws is large enough; kappa-consistent scalar writes for sV)
      {
        const int srow = tid >> 2, l0 = tid & 3, sdb = l0 * 16;
        const float* src = Kf + (size_t)(bh * NKEY + j0 + srow) * DH + sdb;
        const float4 a0 = *(const float4*)(src + 0);
        const float4 a1 = *(const float4*)(src + 4);
        const float4 a2 = *(const float4*)(src + 8);
        const float4 a3 = *(const float4*)(src + 12);
        bf16x8 b0, b1;
        b0[0]=f2bf(a0.x); b0[1]=f2bf(a0.y); b0[2]=f2bf(a0.z); b0[3]=f2bf(a0.w);
        b0[4]=f2bf(a1.x); b0[5]=f2bf(a1.y); b0[6]=f2bf(a1.z); b0[7]=f2bf(a1.w);
        b1[0]=f2bf(a2.x); b1[1]=f2bf(a2.y); b1[2]=f2bf(a2.z); b1[3]=f2bf(a2.w);
        b1[4]=f2bf(a3.x); b1[5]=f2bf(a3.y); b1[6]=f2bf(a3.z); b1[7]=f2bf(a3.w);
        const int s7 = srow & 7;
        *(bf16x8*)&sK[srow * 64 + (((2 * l0)     ^ s7) * 8)] = b0;
        *(bf16x8*)&sK[srow * 64 + (((2 * l0 + 1) ^ s7) * 8)] = b1;
      }
      {
        const int vdb = (tid & 15) * 4, vkb = (tid >> 4) * 4;
        const float* src = Vf + (size_t)(bh * NKEY + j0 + vkb) * DH + vdb;
#pragma unroll
        for (int m = 0; m < 4; ++m) {             // key vkb+m
          const float4 rr = *(const float4*)(src + m * DH);
          const int k   = vkb + m;
          const int kap = (k & 15) * 4 + (k >> 4);
#pragma unroll
          for (int jj = 0; jj < 4; ++jj) {
            const int d = vdb + jj;
            const float fv = (jj == 0) ? rr.x : (jj == 1) ? rr.y : (jj == 2) ? rr.z : rr.w;
            sV[d * 64 + (((kap >> 3) ^ (d & 7)) * 8) + (kap & 7)] = f2bf(fv);
          }
        }
      }
      if (t < NTILE - 1) {
        const short* src = peT + (size_t)t * 64 * 64;   // already swizzled
        short* db = sPE + (size_t)(t & 1) * 4096;
        *(bf16x8*)&db[tid * 16]     = *(const bf16x8*)(src + tid * 16);
        *(bf16x8*)&db[tid * 16 + 8] = *(const bf16x8*)(src + tid * 16 + 8);
      }
    }
    __syncthreads();

    // ---- curPw[m] = Q @ PE over rel col (4t-w+m)*16..+15 (per-wave window).
    // Out-of-range cols read defined-but-stale LDS; killed by the band mask.
#pragma unroll
    for (int m = 0; m < 4; ++m) {
      const int colIdx = 4 * t - w + m;
      const int base = ((colIdx >> 2) & 1) * 4096 + ((colIdx & 3) * 16 + li) * 64;
      f32x4 c = (f32x4){0.f, 0.f, 0.f, 0.f};
#pragma unroll
      for (int ks = 0; ks < 2; ++ks) {
        const int gs = (((ks * 4 + quad) ^ (li & 7)) * 8);
        const bf16x8 b = *(bf16x8*)&sPE[base + gs];
        c = __builtin_amdgcn_mfma_f32_16x16x32_bf16(aq[ks], b, c, 0, 0, 0);
      }
      curPw[m] = c;
    }

    // ---- S = Q @ K^T
    f32x4 cs[4];
#pragma unroll
    for (int nt = 0; nt < 4; ++nt) {
      f32x4 c = (f32x4){0.f, 0.f, 0.f, 0.f};
#pragma unroll
      for (int ks = 0; ks < 2; ++ks) {
        const int gs = (((ks * 4 + quad) ^ (li & 7)) * 8);
        const bf16x8 b = *(bf16x8*)&sK[(nt * 16 + li) * 64 + gs];
        c = __builtin_amdgcn_mfma_f32_16x16x32_bf16(aq[ks], b, c, 0, 0, 0);
      }
      cs[nt] = c;
    }

    // ---- diagonal gather (3 packed shuffles per r) + no-max softmax
    // dl = (nt-w)*16 + e, e = li - quad*4 - r.  pos(nt) = ge ? cur[nt]
    // : (nt ? cur[nt-1] : prevw3).  cur pairs travel as bf16x2.
#pragma unroll
    for (int r = 0; r < 4; ++r) {
      const int e       = li - quad * 4 - r;          // in [-15, 15]
      const bool ge     = (e >= 0);
      const int srcLane = quad * 16 + (e & 15);
      const float shm = __shfl(prevw3[r], srcLane);
      const unsigned pk01 = packbf(curPw[0][r], curPw[1][r]);
      const unsigned pk23 = packbf(curPw[2][r], curPw[3][r]);
      const unsigned s01 = (unsigned)__shfl((int)pk01, srcLane);
      const unsigned s23 = (unsigned)__shfl((int)pk23, srcLane);
      const float sh0 = bf2f((short)(s01 & 0xffffu));
      const float sh1 = bf2f((short)(s01 >> 16));
      const float sh2 = bf2f((short)(s23 & 0xffffu));
      const float sh3 = bf2f((short)(s23 >> 16));
      const float pos0 = ge ? sh0 : shm;
      const float pos1 = ge ? sh1 : sh0;
      const float pos2 = ge ? sh2 : sh1;
      const float pos3 = ge ? sh3 : sh2;
      float p0 = __builtin_exp2f((cs[0][r] + pos0) * SCL_LOG2E);
      float p1 = __builtin_exp2f((cs[1][r] + pos1) * SCL_LOG2E);
      float p2 = __builtin_exp2f((cs[2][r] + pos2) * SCL_LOG2E);
      float p3 = __builtin_exp2f((cs[3][r] + pos3) * SCL_LOG2E);
      if (t == 0) {                 // valid iff dl>=0: nt>w || (nt==w && ge)
        p0 = (0 > w || (0 == w && ge)) ? p0 : 0.f;
        p1 = (1 > w || (1 == w && ge)) ? p1 : 0.f;
        p2 = (2 > w || (2 == w && ge)) ? p2 : 0.f;
        p3 = (3 > w || (3 == w && ge)) ? p3 : 0.f;
      } else if (t == NTILE - 1) {  // valid iff dl<0: nt<w || (nt==w && !ge)
        p0 = (0 < w || (0 == w && !ge)) ? p0 : 0.f;
        p1 = (1 < w || (1 == w && !ge)) ? p1 : 0.f;
        p2 = (2 < w || (2 == w && !ge)) ? p2 : 0.f;
        p3 = (3 < w || (3 == w && !ge)) ? p3 : 0.f;
      }
      l_i[r] += (p0 + p1) + (p2 + p3);
      // kappa-order store: lane li's keys nt*16+li -> kappa = 4*li + nt,
      // contiguous => one b64. Granule (li>>1) ^ (rowA&7), offset (li&1)*4.
      const int rowA = rbase + r;
      const bf16x4 pk = {f2bf(p0), f2bf(p1), f2bf(p2), f2bf(p3)};
      *(bf16x4*)&sPA[rowA * 64 + (((li >> 1) ^ (rowA & 7)) * 8) + (li & 1) * 4] = pk;
    }
    prevw3 = curPw[3];

    // ---- O += P @ V  (kappa-ordered contraction on both operands)
#pragma unroll
    for (int ks = 0; ks < 2; ++ks) {
      const int rowA = w * 16 + li;
      const bf16x8 ap =
          *(bf16x8*)&sPA[rowA * 64 + (((ks * 4 + quad) ^ (rowA & 7)) * 8)];
#pragma unroll
      for (int nt = 0; nt < 4; ++nt) {
        const int d  = nt * 16 + li;
        const int gs = (((ks * 4 + quad) ^ (d & 7)) * 8);
        const bf16x8 bv = *(bf16x8*)&sV[d * 64 + gs];
        acco[nt] = __builtin_amdgcn_mfma_f32_16x16x32_bf16(ap, bv, acco[nt], 0, 0, 0);
      }
    }
  }

  // ---- epilogue: reduce l across the 16 lanes holding each row, out = O / l
#pragma unroll
  for (int r = 0; r < 4; ++r) {
    float l = l_i[r];
    l += __shfl_xor(l, 1);
    l += __shfl_xor(l, 2);
    l += __shfl_xor(l, 4);
    l += __shfl_xor(l, 8);
    const float inv = 1.0f / l;
#pragma unroll
    for (int nt = 0; nt < 4; ++nt) {
      Out[(size_t)(bh * MQ + i0 + rbase + r) * DH + nt * 16 + li] = acco[nt][r] * inv;
    }
  }
}

extern "C" void kernel_launch(void* const* d_in, const int* in_sizes, int n_in,
                              void* d_out, int out_size, void* d_ws, size_t ws_size,
                              hipStream_t stream) {
  const float* q  = (const float*)d_in[0];  // [64,1024,64]
  const float* k  = (const float*)d_in[1];  // [64,2048,64]
  const float* v  = (const float*)d_in[2];  // [64,2048,64]
  const float* pe = (const float*)d_in[3];  // [1,64,1024]
  float* out = (float*)d_out;               // [64,1024,64] f32
  short* peT = (short*)d_ws;
  short* Kb  = (short*)((char*)d_ws + OFF_K);
  short* Vb  = (short*)((char*)d_ws + OFF_V);
  const bool preconv = ws_size >= WS_NEED;  // constant across calls: capture-safe

  dim3 grid(MQ / 64, BHN);
  if (preconv) {
    prep_fused<<<4352, 256, 0, stream>>>(pe, k, v, peT, Kb, Vb);
    seq_attn_kernel<true><<<grid, 256, 0, stream>>>(q, k, v, peT, Kb, Vb, out);
  } else {
    // fallback still needs peT
    prep_fused<<<256, 256, 0, stream>>>(pe, k, v, peT, Kb, Vb);
    seq_attn_kernel<false><<<grid, 256, 0, stream>>>(q, k, v, peT, Kb, Vb, out);
  }
}